// Round 5
// baseline (64.861 us; speedup 1.0000x reference)
//
#include <hip/hip_runtime.h>
#include <hip/hip_bf16.h>
#include <math.h>

typedef __attribute__((ext_vector_type(8))) short bf16x8;
typedef __attribute__((ext_vector_type(4))) float f32x4;

static constexpr float TEMP_INV  = 1.0f / 0.07f;
static constexpr float C_MARGIN  = 0.5f;
static constexpr float T_MARGIN  = 1.0f;
static constexpr float ALPHA     = 0.25f;
static constexpr float SMOOTHING = 0.1f;
static constexpr int   CAP       = 24;    // max positives tracked per row (incl. self)

__device__ __forceinline__ void gload_lds16(const void* g, void* l) {
    __builtin_amdgcn_global_load_lds(
        (const __attribute__((address_space(1))) void*)g,
        (__attribute__((address_space(3))) void*)l,
        16, 0, 0);
}

__device__ __forceinline__ unsigned short f2bf(float x) {
    __hip_bfloat16 h = __float2bfloat16(x);   // RNE
    return *reinterpret_cast<unsigned short*>(&h);
}

// ---- prep: F->bf16, exact fp32 norms, exact positive-distance lists -------
// One wave per row. Positive list = {0 (self)} ∪ {d_ij : labels match, j!=i},
// each d from an exact fp32 full-wave dot product (avg ~2 matches/row).
__global__ __launch_bounds__(256) void prep_kernel(
    const float* __restrict__ F, const int* __restrict__ labels,
    unsigned short* __restrict__ Fb, float* __restrict__ diag,
    float* __restrict__ inv_norm, int* __restrict__ posCnt,
    float* __restrict__ posD, int B, int D) {
    const int row  = blockIdx.x * 4 + (threadIdx.x >> 6);
    const int lane = threadIdx.x & 63;
    const float4* Fr  = (const float4*)(F + (size_t)row * D);
    ushort4*      Fbr = (ushort4*)(Fb + (size_t)row * D);
    const int n4 = D >> 2;

    float s = 0.0f;
    for (int idx = lane; idx < n4; idx += 64) {
        float4 v = Fr[idx];
        s += v.x * v.x + v.y * v.y + v.z * v.z + v.w * v.w;
        ushort4 o;
        o.x = f2bf(v.x); o.y = f2bf(v.y); o.z = f2bf(v.z); o.w = f2bf(v.w);
        Fbr[idx] = o;
    }
#pragma unroll
    for (int off = 32; off > 0; off >>= 1) s += __shfl_xor(s, off, 64);
    const float ri = s;                       // all lanes hold r_i
    if (lane == 0) {
        diag[row] = ri;
        inv_norm[row] = 1.0f / sqrtf(ri);
        posD[(size_t)row * CAP] = 0.0f;       // self-pair distance
    }

    const int li = labels[row];
    int cnt = 1;
    for (int j0 = 0; j0 < B; j0 += 64) {
        int lj = labels[j0 + lane];
        unsigned long long mk = __ballot(lj == li);
        if (row >= j0 && row < j0 + 64) mk &= ~(1ULL << (row - j0));
        while (mk) {
            const int b = __builtin_ctzll(mk);
            mk &= mk - 1;
            const float4* Fj = (const float4*)(F + (size_t)(j0 + b) * D);
            float dp = 0.0f, rj = 0.0f;
            for (int idx = lane; idx < n4; idx += 64) {
                float4 a = Fr[idx], c = Fj[idx];
                dp += a.x * c.x + a.y * c.y + a.z * c.z + a.w * c.w;
                rj += c.x * c.x + c.y * c.y + c.z * c.z + c.w * c.w;
            }
#pragma unroll
            for (int off = 32; off > 0; off >>= 1) {
                dp += __shfl_xor(dp, off, 64);
                rj += __shfl_xor(rj, off, 64);
            }
            if (lane == 0 && cnt < CAP) {
                float d2 = ri - 2.0f * dp + rj;
                posD[(size_t)row * CAP + cnt] = (d2 > 0.0f) ? sqrtf(d2) : 0.0f;
            }
            ++cnt;
        }
    }
    if (lane == 0) posCnt[row] = (cnt < CAP) ? cnt : CAP;
}

// ---- main: block-specialized. Tiles: MFMA gram + in-register loss epilogue.
//      Extra blocks: per-row focal/label-smooth softmax. No atomics. -------
__global__ __launch_bounds__(256) void main_kernel(
    const unsigned short* __restrict__ Fb, const float* __restrict__ diag,
    const float* __restrict__ inv_norm, const int* __restrict__ labels,
    const int* __restrict__ posCnt, const float* __restrict__ posD,
    const float* __restrict__ pred, const int* __restrict__ target,
    float* __restrict__ partialT, float* __restrict__ partialCE,
    int B, int D, int C, float off_const, int tilesX) {
    __shared__ unsigned short As[2][128 * 32];
    __shared__ unsigned short Bs[2][128 * 32];
    __shared__ int   labR[128], labC[128], cntR[128];
    __shared__ float rI[128], rJ[128], iI[128], iJ[128];
    __shared__ float pDs[128 * CAP];
    __shared__ float red[12];

    const int nTiles = tilesX * tilesX;
    const int tid = threadIdx.x;
    const int lane = tid & 63, wid = tid >> 6;

    if (blockIdx.x < nTiles) {
        // ================= gram tile + fused loss epilogue =================
        const int rowBase = (blockIdx.x / tilesX) * 128;
        const int colBase = (blockIdx.x % tilesX) * 128;
        const int w = wid, l = lane;
        const int wr = (w >> 1) * 64;
        const int wc = (w & 1) * 64;
        const int half = l >> 4;     // 16B k-slot 0..3
        const int rr   = l & 15;

        const unsigned short* FA = Fb + (size_t)rowBase * D;
        const unsigned short* FB = Fb + (size_t)colBase * D;

        // stage epilogue metadata (visible after first in-loop barrier)
        if (tid < 128) {
            labR[tid] = labels[rowBase + tid];
            rI[tid]   = diag[rowBase + tid];
            iI[tid]   = inv_norm[rowBase + tid];
            cntR[tid] = posCnt[rowBase + tid];
        } else {
            const int t = tid - 128;
            labC[t] = labels[colBase + t];
            rJ[t]   = diag[colBase + t];
            iJ[t]   = inv_norm[colBase + t];
        }
        {
            const float4* src = (const float4*)(posD + (size_t)rowBase * CAP);
            float4* dst = (float4*)pDs;
            for (int k = tid; k < (128 * CAP) / 4; k += 256) dst[k] = src[k];
        }

        f32x4 acc[4][4];
#pragma unroll
        for (int m = 0; m < 4; ++m)
#pragma unroll
            for (int n = 0; n < 4; ++n) acc[m][n] = (f32x4){0.f, 0.f, 0.f, 0.f};

        auto stage = [&](int buf, int k0) {
#pragma unroll
            for (int c = 0; c < 2; ++c) {
                const int chunk = c * 256 + w * 64 + l;   // 16B chunk, 0..511
                const int r2 = chunk >> 2;                // tile row 0..127
                const int ss = (l & 3) ^ (r2 & 3);        // pre-swizzled slot
                const size_t eoff = (size_t)r2 * D + k0 + ss * 8;
                gload_lds16(FA + eoff, &As[buf][(c * 256 + w * 64) * 8]);
                gload_lds16(FB + eoff, &Bs[buf][(c * 256 + w * 64) * 8]);
            }
        };

        const int NT = D / 32;
        stage(0, 0);
        __syncthreads();
        int cur = 0;
        for (int t = 0; t < NT; ++t) {
            if (t + 1 < NT) stage(cur ^ 1, (t + 1) * 32);
            bf16x8 af[4], bfv[4];
#pragma unroll
            for (int f = 0; f < 4; ++f) {
                const int ar = wr + f * 16 + rr;
                af[f]  = *(const bf16x8*)(&As[cur][ar * 32 + ((half ^ (ar & 3)) * 8)]);
                const int br = wc + f * 16 + rr;
                bfv[f] = *(const bf16x8*)(&Bs[cur][br * 32 + ((half ^ (br & 3)) * 8)]);
            }
#pragma unroll
            for (int m = 0; m < 4; ++m)
#pragma unroll
                for (int n = 0; n < 4; ++n)
                    acc[m][n] = __builtin_amdgcn_mfma_f32_16x16x32_bf16(
                        af[m], bfv[n], acc[m][n], 0, 0, 0);
            __syncthreads();
            cur ^= 1;
        }

        // -------- epilogue: loss terms on fp32 accumulators in registers ---
        float pos = 0.0f, neg = 0.0f, trip = 0.0f;
#pragma unroll
        for (int m = 0; m < 4; ++m) {
            const int ilBase = wr + m * 16 + half * 4;
#pragma unroll
            for (int n = 0; n < 4; ++n) {
                const int jl = wc + n * 16 + rr;
                const int lj = labC[jl];
                const float rj = rJ[jl], ij = iJ[jl];
                const int jg = colBase + jl;
#pragma unroll
                for (int r = 0; r < 4; ++r) {
                    const int il = ilBase + r;
                    const float g = acc[m][n][r];
                    float sim = g * iI[il] * ij;
                    const float d2 = rI[il] - 2.0f * g + rj;
                    float d = (d2 > 0.0f) ? sqrtf(d2) : 0.0f;
                    if (rowBase + il == jg) { sim = 1.0f; d = 0.0f; }
                    if (labR[il] == lj) {
                        pos += -logf(expf(sim * TEMP_INV) + 1e-8f);
                        neg += C_MARGIN;             // relu(0.5 - 0)
                    } else {
                        neg += fmaxf(C_MARGIN - sim, 0.0f);
                        const int c = cntR[il];
                        const float* pd = &pDs[il * CAP];
                        for (int p = 0; p < c; ++p)
                            trip += fmaxf(pd[p] + T_MARGIN - d, 0.0f);
                    }
                }
            }
        }

        float r0 = pos, r1 = neg, r2 = trip;
#pragma unroll
        for (int off = 32; off > 0; off >>= 1) {
            r0 += __shfl_down(r0, off, 64);
            r1 += __shfl_down(r1, off, 64);
            r2 += __shfl_down(r2, off, 64);
        }
        if (lane == 0) { red[wid] = r0; red[4 + wid] = r1; red[8 + wid] = r2; }
        __syncthreads();
        if (tid == 0) {
            float4 o;
            o.x = red[0] + red[1] + red[2] + red[3];
            o.y = red[4] + red[5] + red[6] + red[7];
            o.z = red[8] + red[9] + red[10] + red[11];
            o.w = 0.0f;
            *(float4*)(partialT + (size_t)blockIdx.x * 4) = o;
        }
    } else {
        // ================= ce row: focal + label smoothing =================
        const int i = blockIdx.x - nTiles;
        const float* prow = pred + (size_t)i * C;
        const float tlogit = prow[target[i]];
        const int Cv = C >> 2;

        float m = -1e30f, s = 0.0f, sp = 0.0f;
        for (int idx = tid; idx < Cv; idx += 256) {
            float4 v = ((const float4*)prow)[idx];
            float mv = fmaxf(fmaxf(v.x, v.y), fmaxf(v.z, v.w));
            if (mv > m) { s *= expf(m - mv); m = mv; }
            s += expf(v.x - m) + expf(v.y - m) + expf(v.z - m) + expf(v.w - m);
            sp += v.x + v.y + v.z + v.w;
        }
        for (int j = Cv * 4 + tid; j < C; j += 256) {   // scalar tail
            float v = prow[j];
            if (v > m) { s *= expf(m - v); m = v; }
            s += expf(v - m);
            sp += v;
        }
#pragma unroll
        for (int off = 32; off > 0; off >>= 1) {
            float mo = __shfl_down(m, off, 64);
            float so = __shfl_down(s, off, 64);
            sp += __shfl_down(sp, off, 64);
            float mx = fmaxf(m, mo);
            s = s * expf(m - mx) + so * expf(mo - mx);
            m = mx;
        }
        if (lane == 0) { red[wid] = m; red[4 + wid] = s; red[8 + wid] = sp; }
        __syncthreads();
        if (tid == 0) {
            float mm = red[0], ss = red[4], spT = red[8];
#pragma unroll
            for (int q = 1; q < 4; ++q) {
                float mo = red[q], so = red[4 + q];
                float mn = fmaxf(mm, mo);
                ss = ss * expf(mm - mn) + so * expf(mo - mn);
                mm = mn;
                spT += red[8 + q];
            }
            float lse = mm + logf(ss);
            float tl  = tlogit - lse;
            float ce  = -tl;
            float pt  = expf(tl);
            float omp = 1.0f - pt;
            float focal = ALPHA * omp * omp * ce;       // gamma = 2
            float sumlogp = spT - (float)C * lse;
            float lsv = -(off_const * sumlogp + ((1.0f - SMOOTHING) - off_const) * tl);
            partialCE[(size_t)i * 2]     = focal;
            partialCE[(size_t)i * 2 + 1] = lsv;
        }
    }
}

// ---------------- final reduce ----------------
__global__ __launch_bounds__(256) void reduce_kernel(
    const float* __restrict__ partialT, const float* __restrict__ partialCE,
    float* __restrict__ out, int B, int nTiles) {
    __shared__ float red[4][5];
    const int tid = threadIdx.x;
    float s[5] = {0.f, 0.f, 0.f, 0.f, 0.f};
    for (int t = tid; t < nTiles; t += 256) {
        float4 v = *(const float4*)(partialT + (size_t)t * 4);
        s[0] += v.x; s[1] += v.y; s[2] += v.z;
    }
    for (int t = tid; t < (B * 2) / 4; t += 256) {
        float4 v = *(const float4*)(partialCE + (size_t)t * 4);
        s[3] += v.x + v.z; s[4] += v.y + v.w;
    }
#pragma unroll
    for (int off = 32; off > 0; off >>= 1) {
#pragma unroll
        for (int k = 0; k < 5; ++k) s[k] += __shfl_down(s[k], off, 64);
    }
    const int lane = tid & 63, wid = tid >> 6;
    if (lane == 0) {
#pragma unroll
        for (int k = 0; k < 5; ++k) red[wid][k] = s[k];
    }
    __syncthreads();
    if (tid == 0) {
        float t[5];
#pragma unroll
        for (int k = 0; k < 5; ++k)
            t[k] = red[0][k] + red[1][k] + red[2][k] + red[3][k];
        double invB2 = 1.0 / ((double)B * (double)B);
        float lc = (float)(((double)t[0] + (double)t[1]) * invB2);
        float lt = (float)((double)t[2] / ((double)B + 1e-8));
        float lf = t[3] / (float)B;
        float ls = t[4] / (float)B;
        out[0] = lc;
        out[1] = lt;
        out[2] = lf;
        out[3] = ls;
        out[4] = 0.1f * lc + 0.1f * lt + 0.4f * lf + 0.4f * ls;
    }
}

// ---------------- launch ----------------
extern "C" void kernel_launch(void* const* d_in, const int* in_sizes, int n_in,
                              void* d_out, int out_size, void* d_ws, size_t ws_size,
                              hipStream_t stream) {
    const float* pred     = (const float*)d_in[0];
    const int*   target   = (const int*)d_in[1];
    const float* features = (const float*)d_in[2];
    const int B = in_sizes[1];
    const int C = in_sizes[0] / B;
    const int D = in_sizes[2] / B;
    float* out = (float*)d_out;
    const int tilesX = B / 128;
    const int nTiles = tilesX * tilesX;

    // workspace layout (~2.3 MB for B=2048, D=512)
    float* partialT  = (float*)d_ws;                       // nTiles*4 floats
    float* partialCE = partialT + (size_t)nTiles * 4;      // B*2 floats
    float* diag      = partialCE + (size_t)B * 2;          // B
    float* inv_norm  = diag + B;                           // B
    int*   posCnt    = (int*)(inv_norm + B);               // B
    float* posD      = (float*)(posCnt + B);               // B*CAP
    unsigned short* Fb = (unsigned short*)(posD + (size_t)B * CAP);  // B*D bf16

    prep_kernel<<<B / 4, 256, 0, stream>>>(features, target, Fb, diag,
                                           inv_norm, posCnt, posD, B, D);

    float off_const = SMOOTHING / (float)(C - 1);
    main_kernel<<<nTiles + B, 256, 0, stream>>>(
        Fb, diag, inv_norm, target, posCnt, posD, pred, target,
        partialT, partialCE, B, D, C, off_const, tilesX);

    reduce_kernel<<<1, 256, 0, stream>>>(partialT, partialCE, out, B, nTiles);
}